// Round 1
// baseline (1716.311 us; speedup 1.0000x reference)
//
#include <hip/hip_runtime.h>
#include <hip/hip_fp16.h>

typedef _Float16 f16;
typedef __attribute__((ext_vector_type(4))) _Float16 f16x4;
typedef __attribute__((ext_vector_type(8))) _Float16 f16x8;
typedef __attribute__((ext_vector_type(4))) float f32x4;

#define NTOK    16384      // 4 * 4096 tokens
#define SEQ     4096
#define HIDDEN  2048
#define DMODEL  6144
#define VOCAB_MASK 131071  // BIGRAM_VOCAB - 1 (power of two)
#define HASH_MULT 1000003LL

#define BM 128
#define BN 128
#define BK 64

// async global->LDS, 16B per lane, dest = wave-uniform base + lane*16
#define GLDS16(gsrc, ldst)                                                        \
  __builtin_amdgcn_global_load_lds(                                               \
      (const __attribute__((address_space(1))) void*)(gsrc),                      \
      (__attribute__((address_space(3))) void*)(ldst), 16, 0, 0)

// ---------------------------------------------------------------------------
// Kernel 1: proj_w fp32 [6144][2048] -> fp16 (same layout, linear convert)
// ---------------------------------------------------------------------------
__global__ void conv_proj(const float* __restrict__ src, f16* __restrict__ dst) {
  int i = blockIdx.x * blockDim.x + threadIdx.x;   // one float4 per thread
  const float4 v = reinterpret_cast<const float4*>(src)[i];
  f16x4 o;
  o[0] = (f16)v.x; o[1] = (f16)v.y; o[2] = (f16)v.z; o[3] = (f16)v.w;
  reinterpret_cast<f16x4*>(dst)[i] = o;
}

// ---------------------------------------------------------------------------
// Kernel 2: hash + gather + convert.  One block per token.
// Ap[t][k] = fp16(table[bigram_idx(t)][k])
// ---------------------------------------------------------------------------
__global__ void gather_conv(const int* __restrict__ ids,
                            const float* __restrict__ table,
                            f16* __restrict__ Ap) {
  const int t   = blockIdx.x;
  const int tid = threadIdx.x;

  const int cur  = ids[t];
  const int prev = ((t & (SEQ - 1)) == 0) ? 0 : ids[t - 1];
  const long long h = (long long)prev * HASH_MULT + (long long)cur;
  const int idx = (int)(h & (long long)VOCAB_MASK);

  const float* srow = table + (size_t)idx * HIDDEN;
  f16* drow = Ap + (size_t)t * HIDDEN;

  const int k = tid * 8;                       // 256 threads * 8 = 2048
  const float4 v0 = *reinterpret_cast<const float4*>(srow + k);
  const float4 v1 = *reinterpret_cast<const float4*>(srow + k + 4);
  f16x8 o;
  o[0] = (f16)v0.x; o[1] = (f16)v0.y; o[2] = (f16)v0.z; o[3] = (f16)v0.w;
  o[4] = (f16)v1.x; o[5] = (f16)v1.y; o[6] = (f16)v1.z; o[7] = (f16)v1.w;
  *reinterpret_cast<f16x8*>(drow + k) = o;
}

// ---------------------------------------------------------------------------
// Kernel 3: C[M=16384][N=6144] = A[M][K=2048] * B[N][K]^T   (fp16 in, fp32 out)
// m97-style: 128x128 tile, BK=64, 4 waves (2x2), 64x64 per wave,
// global_load_lds width-16 staging, ds_read_b128 frags, mfma 16x16x32 f16.
// ---------------------------------------------------------------------------
__global__ void gemm_f16(const f16* __restrict__ A,
                         const f16* __restrict__ B,
                         float* __restrict__ C) {
  constexpr int M = NTOK, N = DMODEL, K = HIDDEN;
  __shared__ f16 As[BM][BK];   // 16 KB
  __shared__ f16 Bs[BN][BK];   // 16 KB

  const int tid  = threadIdx.x;
  const int wave = tid >> 6;
  const int lane = tid & 63;
  const int bm = blockIdx.y, bn = blockIdx.x;

  const int wr = wave >> 1, wc = wave & 1;   // 2x2 wave grid, 64x64 each
  const int lr = lane & 15;                  // fragment row/col
  const int lk = lane >> 4;                  // k-group (0..3)

  f32x4 acc[4][4];
#pragma unroll
  for (int m = 0; m < 4; ++m)
#pragma unroll
    for (int n = 0; n < 4; ++n) acc[m][n] = (f32x4){0.f, 0.f, 0.f, 0.f};

  // staging addresses: wave w fills rows [32w, 32w+32) of each tile in 4
  // instructions of 8 rows; lane covers row 8*i + lane/8, 16B chunk lane%8.
  const int srow = wave * 32 + (lane >> 3);
  const int scol = (lane & 7) * 8;
  const f16* Ag = A + ((size_t)(bm * BM + srow)) * K + scol;
  const f16* Bg = B + ((size_t)(bn * BN + srow)) * K + scol;

  for (int k0 = 0; k0 < K; k0 += BK) {
#pragma unroll
    for (int i = 0; i < 4; ++i) {
      GLDS16(Ag + (size_t)i * 8 * K + k0, &As[wave * 32 + i * 8][0]);
      GLDS16(Bg + (size_t)i * 8 * K + k0, &Bs[wave * 32 + i * 8][0]);
    }
    __syncthreads();   // compiler drains vmcnt before s_barrier

#pragma unroll
    for (int kk = 0; kk < 2; ++kk) {
      f16x8 af[4], bfr[4];
#pragma unroll
      for (int m = 0; m < 4; ++m)
        af[m] = *reinterpret_cast<const f16x8*>(&As[wr * 64 + m * 16 + lr][kk * 32 + lk * 8]);
#pragma unroll
      for (int n = 0; n < 4; ++n)
        bfr[n] = *reinterpret_cast<const f16x8*>(&Bs[wc * 64 + n * 16 + lr][kk * 32 + lk * 8]);
#pragma unroll
      for (int m = 0; m < 4; ++m)
#pragma unroll
        for (int n = 0; n < 4; ++n)
          acc[m][n] = __builtin_amdgcn_mfma_f32_16x16x32_f16(af[m], bfr[n], acc[m][n], 0, 0, 0);
    }
    __syncthreads();
  }

  // epilogue: C/D layout col = lane&15, row = (lane>>4)*4 + reg
  const size_t crow0 = (size_t)(bm * BM + wr * 64) + (lane >> 4) * 4;
  const int    ccol0 = bn * BN + wc * 64 + (lane & 15);
#pragma unroll
  for (int m = 0; m < 4; ++m) {
#pragma unroll
    for (int n = 0; n < 4; ++n) {
      float* cp = C + (crow0 + m * 16) * (size_t)N + ccol0 + n * 16;
#pragma unroll
      for (int r = 0; r < 4; ++r) cp[(size_t)r * N] = acc[m][n][r];
    }
  }
}

// ---------------------------------------------------------------------------
extern "C" void kernel_launch(void* const* d_in, const int* in_sizes, int n_in,
                              void* d_out, int out_size, void* d_ws, size_t ws_size,
                              hipStream_t stream) {
  const int*   ids   = (const int*)d_in[0];     // [4,4096] token ids
  const float* table = (const float*)d_in[1];   // [131072][2048]
  const float* projw = (const float*)d_in[2];   // [6144][2048]
  float* out = (float*)d_out;                   // [16384][6144]

  f16* Bp = (f16*)d_ws;                                          // 25.2 MB
  f16* Ap = (f16*)((char*)d_ws + (size_t)DMODEL * HIDDEN * 2);   // 67.1 MB

  conv_proj<<<dim3((DMODEL * HIDDEN / 4) / 256), 256, 0, stream>>>(projw, Bp);
  gather_conv<<<dim3(NTOK), 256, 0, stream>>>(ids, table, Ap);
  gemm_f16<<<dim3(DMODEL / BN, NTOK / BM), 256, 0, stream>>>(Ap, Bp, out);
}